// Round 4
// baseline (355.487 us; speedup 1.0000x reference)
//
#include <hip/hip_runtime.h>

#define EPS 1e-10f
#define FAR_DELTA 1e10f

// Persistent grid + register-double-buffered pipeline.
// One ray per 16-lane group (4 rays/wave, 16 rays per block-iteration).
// Lane j owns samples [j*8, j*8+8). Each loop iteration:
//   1) issue ALL 10 dwordx4 loads for the NEXT ray-group into 'n*' regs
//   2) compute the CURRENT group from 'c*' regs (expf chain, width-16 scan,
//      dot products, width-16 butterfly, store)
//   3) rotate registers.
// No LDS, no __syncthreads -> no vmcnt(0) barrier drain; the compiler's
// per-register s_waitcnt keeps next-iter loads in flight across compute.
__global__ __launch_bounds__(256, 4) void volrend_kernel(
    const float* __restrict__ density,   // [N,128]
    const float* __restrict__ feature,   // [N,128,3]
    const float* __restrict__ depth,     // [N,128]
    float* __restrict__ feat_out,        // [N,3]
    float* __restrict__ depth_out,       // [N]
    int N, int numW)                     // numW = N/16 ray-groups
{
    const int tid  = threadIdx.x;
    const int lane = tid & 63;
    const int wv   = tid >> 6;        // wave in block
    const int j    = lane & 15;       // sublane in ray group
    const int sub  = lane >> 4;       // ray slot in wave
    const int roff = wv * 4 + sub;    // ray offset within the block's 16

    int w = blockIdx.x;
    if (w >= numW) return;

    float4 cdA, cdB, czA, czB, cF0, cF1, cF2, cF3, cF4, cF5;
    float4 ndA, ndB, nzA, nzB, nF0, nF1, nF2, nF3, nF4, nF5;

    // Prologue: issue loads for the first group.
    {
        const int ray = w * 16 + roff;
        const float4* d4 = (const float4*)(density + (size_t)ray * 128 + j * 8);
        const float4* z4 = (const float4*)(depth   + (size_t)ray * 128 + j * 8);
        const float4* f4 = (const float4*)(feature + (size_t)ray * 384 + j * 24);
        cdA = d4[0]; cdB = d4[1]; czA = z4[0]; czB = z4[1];
        cF0 = f4[0]; cF1 = f4[1]; cF2 = f4[2]; cF3 = f4[3]; cF4 = f4[4]; cF5 = f4[5];
    }

    while (w < numW) {
        const int wn = w + gridDim.x;

        // ---- 1) prefetch next group's 10 dwordx4 into 'n*' regs ----
        {
            const int wp  = (wn < numW) ? wn : w;    // clamp: last iter re-loads (harmless)
            const int ray = wp * 16 + roff;
            const float4* d4 = (const float4*)(density + (size_t)ray * 128 + j * 8);
            const float4* z4 = (const float4*)(depth   + (size_t)ray * 128 + j * 8);
            const float4* f4 = (const float4*)(feature + (size_t)ray * 384 + j * 24);
            ndA = d4[0]; ndB = d4[1]; nzA = z4[0]; nzB = z4[1];
            nF0 = f4[0]; nF1 = f4[1]; nF2 = f4[2]; nF3 = f4[3]; nF4 = f4[4]; nF5 = f4[5];
        }

        // ---- 2) compute current group ----
        {
            const int ray = w * 16 + roff;

            float z[8]  = {czA.x, czA.y, czA.z, czA.w, czB.x, czB.y, czB.z, czB.w};
            float dn[8] = {cdA.x, cdA.y, cdA.z, cdA.w, cdB.x, cdB.y, cdB.z, cdB.w};

            // Seam depth from the next lane (same ray for j<15; j==15 uses FAR).
            float znext = __shfl_down(z[0], 1, 64);

            float wl[8];
            float tl  = 1.0f;     // running local product of t
            float adP = 0.0f;     // partial sum w_local * z
            #pragma unroll
            for (int k = 0; k < 8; ++k) {
                float delta = (k < 7) ? (z[k + 1] - z[k])
                                      : ((j == 15) ? FAR_DELTA : (znext - z[7]));
                float ex = __expf(-fmaxf(dn[k], 0.0f) * delta);   // 1 - alpha
                float tk = ex + EPS;
                wl[k] = (1.0f - ex) * tl;
                adP  += wl[k] * z[k];
                tl   *= tk;
            }

            // Width-16 inclusive product scan of lane totals -> exclusive prefix.
            float s = tl;
            #pragma unroll
            for (int off = 1; off < 16; off <<= 1) {
                float v = __shfl_up(s, off, 16);
                if (j >= off) s *= v;
            }
            float excl = __shfl_up(s, 1, 16);
            if (j == 0) excl = 1.0f;

            float f[24] = {cF0.x, cF0.y, cF0.z, cF0.w, cF1.x, cF1.y, cF1.z, cF1.w,
                           cF2.x, cF2.y, cF2.z, cF2.w, cF3.x, cF3.y, cF3.z, cF3.w,
                           cF4.x, cF4.y, cF4.z, cF4.w, cF5.x, cF5.y, cF5.z, cF5.w};

            float a0 = 0.0f, a1 = 0.0f, a2 = 0.0f;
            #pragma unroll
            for (int k = 0; k < 8; ++k) {
                a0 += wl[k] * f[3 * k + 0];
                a1 += wl[k] * f[3 * k + 1];
                a2 += wl[k] * f[3 * k + 2];
            }

            a0 *= excl; a1 *= excl; a2 *= excl;
            float ad = adP * excl;

            #pragma unroll
            for (int off = 8; off >= 1; off >>= 1) {
                a0 += __shfl_xor(a0, off, 16);
                a1 += __shfl_xor(a1, off, 16);
                a2 += __shfl_xor(a2, off, 16);
                ad += __shfl_xor(ad, off, 16);
            }

            if (j == 0) {
                feat_out[(size_t)ray * 3 + 0] = a0;
                feat_out[(size_t)ray * 3 + 1] = a1;
                feat_out[(size_t)ray * 3 + 2] = a2;
                depth_out[ray] = ad;
            }
        }

        // ---- 3) rotate ----
        cdA = ndA; cdB = ndB; czA = nzA; czB = nzB;
        cF0 = nF0; cF1 = nF1; cF2 = nF2; cF3 = nF3; cF4 = nF4; cF5 = nF5;
        w = wn;
    }
}

extern "C" void kernel_launch(void* const* d_in, const int* in_sizes, int n_in,
                              void* d_out, int out_size, void* d_ws, size_t ws_size,
                              hipStream_t stream) {
    const float* density = (const float*)d_in[0];   // [N,128]
    const float* feature = (const float*)d_in[1];   // [N,128,3]
    const float* depth   = (const float*)d_in[2];   // [N,128]

    const int P = 128;
    const int N = in_sizes[0] / P;                  // 131072

    float* feat_out  = (float*)d_out;                 // [N,3]
    float* depth_out = (float*)d_out + (size_t)N * 3; // [N]

    const int numW = (N + 15) / 16;                 // 8192 ray-groups
    int grid = 1024;                                // persistent: 4 blocks/CU
    if (grid > numW) grid = numW;
    volrend_kernel<<<dim3(grid), dim3(256), 0, stream>>>(
        density, feature, depth, feat_out, depth_out, N, numW);
}